// Round 1
// baseline (4872.286 us; speedup 1.0000x reference)
//
#include <hip/hip_runtime.h>
#include <stdint.h>

typedef unsigned long long ull;

#define NEGINF_ORD 0x007FFFFFu

__device__ __forceinline__ unsigned ordf(float f) {
    unsigned u = __float_as_uint(f);
    return (u & 0x80000000u) ? ~u : (u | 0x80000000u);
}

// ---------------- conv 3x3 + bias + relu ----------------
// in: [2][1024][64][64], Wc: [512][1024][3][3], out x: [2][512][64][64]
#define CK 8
#define ROWSZ 76
#define WSTR 132

__global__ __launch_bounds__(256) void conv3x3_kernel(
    const float* __restrict__ in, const float* __restrict__ Wc,
    const float* __restrict__ bc, float* __restrict__ xout)
{
    __shared__ __align__(16) float Wlds[72 * WSTR];   // [k=c*9+kh*3+kw][o], 37.1 KB
    __shared__ __align__(16) float Ilds[CK * 3 * ROWSZ]; // [c][r][skewed col], 7.1 KB

    const int h  = blockIdx.x;   // 0..63
    const int ot = blockIdx.y;   // 0..3  (128 outputs each)
    const int b  = blockIdx.z;   // 0..1
    const int tid = threadIdx.x;
    const int tx = tid & 15;     // w-group: w = tx*4 .. +3
    const int ty = tid >> 4;     // o-group: o = ty*8 .. +7
    const int c4 = tx * 4;
    const int sk0 = c4 + 4 * (c4 >> 5);
    const int sk1 = (c4 + 4) + 4 * ((c4 + 4) >> 5);
    const int lane = tid & 63, cr = tid >> 6;

    float acc[8][4];
#pragma unroll
    for (int i = 0; i < 8; ++i)
#pragma unroll
        for (int j = 0; j < 4; ++j) acc[i][j] = 0.f;

    const float* wg = Wc + (size_t)(ot * 128) * 9216;

    for (int c0 = 0; c0 < 1024; c0 += CK) {
        __syncthreads();
        // stage weights: 128 o x 72 k, coalesced global (72-elem runs)
#pragma unroll
        for (int r = 0; r < 36; ++r) {
            int e = tid + 256 * r;          // 0..9215
            int o_l = e / 72;
            int k = e - o_l * 72;
            Wlds[k * WSTR + o_l] = wg[o_l * 9216 + c0 * 9 + k];
        }
        // stage input: CK ch x 3 rows x (64 + halo), zero pad
#pragma unroll
        for (int rr = 0; rr < 6; ++rr) {
            int pi = cr + 4 * rr;           // 0..23
            int c = pi / 3, r = pi - 3 * (pi / 3);
            int hin = h - 1 + r;
            float v = 0.f;
            if (hin >= 0 && hin < 64)
                v = in[(((b * 1024 + c0 + c) * 64) + hin) * 64 + lane];
            int col = lane + 1;
            Ilds[(c * 3 + r) * ROWSZ + col + 4 * (col >> 5)] = v;
            if (lane < 2) {
                int col2 = (lane == 0) ? 0 : 65;
                Ilds[(c * 3 + r) * ROWSZ + col2 + 4 * (col2 >> 5)] = 0.f;
            }
        }
        __syncthreads();

        float accc[8][4];
#pragma unroll
        for (int i = 0; i < 8; ++i)
#pragma unroll
            for (int j = 0; j < 4; ++j) accc[i][j] = 0.f;

        for (int c = 0; c < CK; ++c) {
            float xr[3][6];
#pragma unroll
            for (int r = 0; r < 3; ++r) {
                const float* base = Ilds + (c * 3 + r) * ROWSZ;
                float4 v4 = *(const float4*)(base + sk0);
                float2 v2 = *(const float2*)(base + sk1);
                xr[r][0] = v4.x; xr[r][1] = v4.y; xr[r][2] = v4.z; xr[r][3] = v4.w;
                xr[r][4] = v2.x; xr[r][5] = v2.y;
            }
#pragma unroll
            for (int kh = 0; kh < 3; ++kh) {
#pragma unroll
                for (int kw = 0; kw < 3; ++kw) {
                    const float* wr = Wlds + ((c * 3 + kh) * 3 + kw) * WSTR + ty * 8;
                    float4 w0 = *(const float4*)(wr);
                    float4 w1 = *(const float4*)(wr + 4);
#pragma unroll
                    for (int jw = 0; jw < 4; ++jw) {
                        float xv = xr[kh][kw + jw];
                        accc[0][jw] += w0.x * xv;
                        accc[1][jw] += w0.y * xv;
                        accc[2][jw] += w0.z * xv;
                        accc[3][jw] += w0.w * xv;
                        accc[4][jw] += w1.x * xv;
                        accc[5][jw] += w1.y * xv;
                        accc[6][jw] += w1.z * xv;
                        accc[7][jw] += w1.w * xv;
                    }
                }
            }
        }
#pragma unroll
        for (int i = 0; i < 8; ++i)
#pragma unroll
            for (int j = 0; j < 4; ++j) acc[i][j] += accc[i][j];
    }

    // epilogue: + bias, relu, store
#pragma unroll
    for (int i = 0; i < 8; ++i) {
        int o = ot * 128 + ty * 8 + i;
        float bias = bc[o];
        float4 res;
        res.x = fmaxf(acc[i][0] + bias, 0.f);
        res.y = fmaxf(acc[i][1] + bias, 0.f);
        res.z = fmaxf(acc[i][2] + bias, 0.f);
        res.w = fmaxf(acc[i][3] + bias, 0.f);
        *(float4*)&xout[(((b * 512 + o) * 64) + h) * 64 + tx * 4] = res;
    }
}

// ---------------- heads: 1x1 convs + softmax + decode + clip + filter ----------------
__global__ __launch_bounds__(256) void head_kernel(
    const float* __restrict__ x, const float* __restrict__ Wcls,
    const float* __restrict__ bcls, const float* __restrict__ Wbb,
    const float* __restrict__ bbb, const float* __restrict__ meta,
    ull* __restrict__ keys, float4* __restrict__ boxes)
{
    __shared__ __align__(16) float Wl[512 * 20]; // [c][j], 40 KB
    const int b = blockIdx.y, blk = blockIdx.x, tid = threadIdx.x;

#pragma unroll
    for (int r = 0; r < 40; ++r) {
        int L = tid + 256 * r;               // 0..10239
        int c = L / 20, j = L - 20 * c;
        Wl[c * 20 + j] = (j < 4) ? Wcls[j * 512 + c] : Wbb[(j - 4) * 512 + c];
    }
    __syncthreads();

    const int p = blk * 256 + tid;           // spatial position 0..4095
    const float* xb = x + (size_t)(b * 512) * 4096 + p;

    float acc[20];
#pragma unroll
    for (int j = 0; j < 20; ++j) acc[j] = 0.f;

    for (int c0 = 0; c0 < 512; c0 += 64) {
        float at[20];
#pragma unroll
        for (int j = 0; j < 20; ++j) at[j] = 0.f;
        for (int c = c0; c < c0 + 64; ++c) {
            float xv = xb[(size_t)c * 4096];
            const float4* wr = (const float4*)(Wl + c * 20);
            float4 w0 = wr[0], w1 = wr[1], w2 = wr[2], w3 = wr[3], w4 = wr[4];
            at[0] += w0.x * xv;  at[1] += w0.y * xv;  at[2] += w0.z * xv;  at[3] += w0.w * xv;
            at[4] += w1.x * xv;  at[5] += w1.y * xv;  at[6] += w1.z * xv;  at[7] += w1.w * xv;
            at[8] += w2.x * xv;  at[9] += w2.y * xv;  at[10] += w2.z * xv; at[11] += w2.w * xv;
            at[12] += w3.x * xv; at[13] += w3.y * xv; at[14] += w3.z * xv; at[15] += w3.w * xv;
            at[16] += w4.x * xv; at[17] += w4.y * xv; at[18] += w4.z * xv; at[19] += w4.w * xv;
        }
#pragma unroll
        for (int j = 0; j < 20; ++j) acc[j] += at[j];
    }

    float s[4], d[16];
#pragma unroll
    for (int j = 0; j < 4; ++j) s[j] = acc[j] + bcls[j];
#pragma unroll
    for (int j = 0; j < 16; ++j) d[j] = acc[4 + j] + bbb[j];

    // softmax pairs (a, a+2)
    float prob[4];
#pragma unroll
    for (int pr = 0; pr < 2; ++pr) {
        float m = fmaxf(s[pr], s[pr + 2]);
        float e0 = expf(s[pr] - m), e2 = expf(s[pr + 2] - m);
        float sum = e0 + e2;
        prob[pr] = e0 / sum;
        prob[pr + 2] = e2 / sum;
    }

    const float imh1 = meta[b * 3 + 0] - 1.0f;
    const float imw1 = meta[b * 3 + 1] - 1.0f;
    const float minsz = 16.0f * meta[b * 3 + 2];
    const int wp = p & 63, hp = p >> 6;
    const float cx = (float)(wp * 16 + 8), cy = (float)(hp * 16 + 8);

#pragma unroll
    for (int a = 0; a < 4; ++a) {
        float wa = (float)(64 << a);        // square anchors, exact pow2
        float pcx = d[4 * a + 0] * wa + cx;  // products exact (pow2 scale)
        float pcy = d[4 * a + 1] * wa + cy;
        float pw = expf(d[4 * a + 2]) * wa;
        float ph = expf(d[4 * a + 3]) * wa;
        float x1 = pcx - 0.5f * pw, y1 = pcy - 0.5f * ph;
        float x2 = pcx + 0.5f * pw, y2 = pcy + 0.5f * ph;
        x1 = fminf(fmaxf(x1, 0.f), imw1);
        y1 = fminf(fmaxf(y1, 0.f), imh1);
        x2 = fminf(fmaxf(x2, 0.f), imw1);
        y2 = fminf(fmaxf(y2, 0.f), imh1);
        bool keep = (((x2 - x1) + 1.0f) >= minsz) && (((y2 - y1) + 1.0f) >= minsz);
        float sc = keep ? prob[a] : -__builtin_inff();
        int n = p * 4 + a;
        keys[b * 16384 + n] = ((ull)ordf(sc) << 32) | (ull)(unsigned)(16383 - n);
        float4 bx; bx.x = x1; bx.y = y1; bx.z = x2; bx.w = y2;
        boxes[b * 16384 + n] = bx;
    }
}

// ---------------- bitonic sort (descending) over uint64 keys ----------------
__global__ __launch_bounds__(512) void sort_local(ull* __restrict__ keys, int kfirst, int klast)
{
    __shared__ ull s[4096];
    const int b = blockIdx.y, chunk = blockIdx.x, tid = threadIdx.x;
    ull* g = keys + b * 16384 + chunk * 4096;
#pragma unroll
    for (int r = 0; r < 8; ++r) s[tid + 512 * r] = g[tid + 512 * r];
    __syncthreads();
    const int gbase = chunk * 4096;
    for (int k = kfirst; k <= klast; k <<= 1) {
        int j0 = (k >> 1) < 2048 ? (k >> 1) : 2048;
        for (int j = j0; j > 0; j >>= 1) {
#pragma unroll
            for (int pp = 0; pp < 4; ++pp) {
                int p = tid + 512 * pp;                    // pair 0..2047
                int i = ((p & ~(j - 1)) << 1) | (p & (j - 1));
                int l = i + j;
                ull a = s[i], c = s[l];
                bool up = (((gbase + i) & k) == 0);
                bool sw = up ? (a < c) : (c < a);
                if (sw) { s[i] = c; s[l] = a; }
            }
            __syncthreads();
        }
    }
#pragma unroll
    for (int r = 0; r < 8; ++r) g[tid + 512 * r] = s[tid + 512 * r];
}

__global__ __launch_bounds__(256) void sort_global_k(ull* __restrict__ keys, int k, int j)
{
    int t = blockIdx.x * 256 + threadIdx.x;   // 0..16383
    int b = t >> 13, p = t & 8191;
    int i = ((p & ~(j - 1)) << 1) | (p & (j - 1));
    int l = i + j;
    ull* g = keys + b * 16384;
    ull a = g[i], c = g[l];
    bool up = ((i & k) == 0);
    bool sw = up ? (a < c) : (c < a);
    if (sw) { g[i] = c; g[l] = a; }
}

// ---------------- gather top-6000 sorted boxes ----------------
__global__ __launch_bounds__(256) void gather_kernel(
    const ull* __restrict__ keys, const float4* __restrict__ boxes,
    float4* __restrict__ bs, float* __restrict__ as_, ull* __restrict__ valid)
{
    const int b = blockIdx.y;
    const int i = blockIdx.x * 256 + threadIdx.x;  // 0..6143
    bool fin = false;
    float4 box; box.x = 0.f; box.y = 0.f; box.z = 0.f; box.w = 0.f;
    float area = 1.f;
    if (i < 6000) {
        ull k = keys[b * 16384 + i];
        fin = ((unsigned)(k >> 32)) != NEGINF_ORD;
        int idx = 16383 - (int)(k & 0xFFFFFFFFull);
        box = boxes[b * 16384 + idx];
        area = ((box.z - box.x) + 1.0f) * ((box.w - box.y) + 1.0f);
    }
    bs[b * 6144 + i] = box;
    as_[b * 6144 + i] = area;
    ull m = __ballot(fin ? 1 : 0);
    if ((threadIdx.x & 63) == 0) valid[b * 96 + (i >> 6)] = m;
}

// ---------------- sequential greedy NMS (heads monotone in sorted order) ----------------
__global__ __launch_bounds__(1024) void nms_kernel(
    const float4* __restrict__ bs, const float* __restrict__ as_,
    const ull* __restrict__ valid, float* __restrict__ out)
{
    __shared__ unsigned char supp[6144];
    __shared__ int keepL[300];
    __shared__ int jsh;
    __shared__ float4 jbox_sh;
    __shared__ float jarea_sh;
    __shared__ int hp_sh;

    const int b = blockIdx.x, tid = threadIdx.x;

    for (int i = tid; i < 6144; i += 1024) {
        ull w = valid[b * 96 + (i >> 6)];
        supp[i] = ((w >> (i & 63)) & 1ull) ? 0 : 1;  // pre-suppress -inf / padding
    }
    if (tid == 0) hp_sh = 0;
    __syncthreads();

    float4 box[6]; float area[6]; bool sf[6];
#pragma unroll
    for (int q = 0; q < 6; ++q) {
        int i = tid * 6 + q;
        box[q] = bs[b * 6144 + i];
        area[q] = as_[b * 6144 + i];
        sf[q] = (supp[i] != 0);
    }

    for (int t = 0; t < 300; ++t) {
        if (tid == 0) {
            int hp = hp_sh;
            while (hp < 6000 && supp[hp]) hp++;
            int j = (hp < 6000) ? hp : 0;
            if (hp < 6000) { supp[hp] = 1; hp_sh = hp + 1; }
            else hp_sh = hp;
            jsh = j; keepL[t] = j;
            jbox_sh = bs[b * 6144 + j];
            jarea_sh = as_[b * 6144 + j];
        }
        __syncthreads();
        const int j = jsh;
        const float4 jb = jbox_sh;
        const float ja = jarea_sh;
#pragma unroll
        for (int q = 0; q < 6; ++q) {
            int i = tid * 6 + q;
            if (i > j && !sf[q]) {
                float xx1 = fmaxf(jb.x, box[q].x);
                float yy1 = fmaxf(jb.y, box[q].y);
                float xx2 = fminf(jb.z, box[q].z);
                float yy2 = fminf(jb.w, box[q].w);
                float iw = fmaxf((xx2 - xx1) + 1.0f, 0.f);
                float ih = fmaxf((yy2 - yy1) + 1.0f, 0.f);
                float inter = iw * ih;
                float iou = inter / ((ja + area[q]) - inter);
                if (iou > 0.7f) { sf[q] = true; supp[i] = 1; }
            }
        }
        __syncthreads();
    }

    if (tid < 300) {
        int j = keepL[tid];
        float4 bx = bs[b * 6144 + j];
        float* o = out + (size_t)(b * 300 + tid) * 5;
        o[0] = (float)b; o[1] = bx.x; o[2] = bx.y; o[3] = bx.z; o[4] = bx.w;
    }
}

// ---------------- launcher ----------------
extern "C" void kernel_launch(void* const* d_in, const int* in_sizes, int n_in,
                              void* d_out, int out_size, void* d_ws, size_t ws_size,
                              hipStream_t stream) {
    const float* feat  = (const float*)d_in[0];
    const float* meta  = (const float*)d_in[1];
    const float* Wconv = (const float*)d_in[3];
    const float* bconv = (const float*)d_in[4];
    const float* Wcls  = (const float*)d_in[5];
    const float* bcls  = (const float*)d_in[6];
    const float* Wbb   = (const float*)d_in[7];
    const float* bbb   = (const float*)d_in[8];
    float* out = (float*)d_out;

    char* ws = (char*)d_ws;
    float*  x     = (float*)(ws);                       // 16,777,216 B
    ull*    keys  = (ull*)(ws + 16777216);              //    262,144 B
    float4* boxes = (float4*)(ws + 17039360);           //  1,048,576 B
    float4* bsort = (float4*)(ws + 18087936);           //    196,608 B
    float*  asort = (float*)(ws + 18284544);            //     49,152 B
    ull*    valid = (ull*)(ws + 18333696);              //      1,536 B

    conv3x3_kernel<<<dim3(64, 4, 2), 256, 0, stream>>>(feat, Wconv, bconv, x);
    head_kernel<<<dim3(16, 2), 256, 0, stream>>>(x, Wcls, bcls, Wbb, bbb, meta, keys, boxes);
    sort_local<<<dim3(4, 2), 512, 0, stream>>>(keys, 2, 4096);
    sort_global_k<<<64, 256, 0, stream>>>(keys, 8192, 4096);
    sort_local<<<dim3(4, 2), 512, 0, stream>>>(keys, 8192, 8192);
    sort_global_k<<<64, 256, 0, stream>>>(keys, 16384, 8192);
    sort_global_k<<<64, 256, 0, stream>>>(keys, 16384, 4096);
    sort_local<<<dim3(4, 2), 512, 0, stream>>>(keys, 16384, 16384);
    gather_kernel<<<dim3(24, 2), 256, 0, stream>>>(keys, boxes, bsort, asort, valid);
    nms_kernel<<<2, 1024, 0, stream>>>(bsort, asort, valid, out);
}

// Round 2
// 2864.739 us; speedup vs baseline: 1.7008x; 1.7008x over previous
//
#include <hip/hip_runtime.h>
#include <stdint.h>

typedef unsigned long long ull;

#define NEGINF_ORD 0x007FFFFFu

__device__ __forceinline__ unsigned ordf(float f) {
    unsigned u = __float_as_uint(f);
    return (u & 0x80000000u) ? ~u : (u | 0x80000000u);
}

__device__ __forceinline__ void gl16(const float* g, float* l) {
    __builtin_amdgcn_global_load_lds(
        (const __attribute__((address_space(1))) unsigned*)g,
        (__attribute__((address_space(3))) unsigned*)l, 16, 0, 0);
}

// ---------------- tiny prepass kernels ----------------
__global__ __launch_bounds__(256) void zero_fill(float* __restrict__ z) {
    z[threadIdx.x] = 0.f;   // 1KB zero page (256 floats)
}

// W [512][1024][3][3] -> Wt2[ot=4][k=9216][o=128]  (k = c*9 + kh*3 + kw)
__global__ __launch_bounds__(256) void reorder_w(const float* __restrict__ W, float* __restrict__ Wt2) {
    __shared__ float t[16][130];
    const int kb = blockIdx.x * 16;      // 576
    const int ot = blockIdx.y;           // 4
    const int tid = threadIdx.x;
#pragma unroll
    for (int r = 0; r < 8; ++r) {
        int e = tid + 256 * r;           // 0..2047
        int o_l = e >> 4, kk = e & 15;
        t[kk][o_l] = W[(size_t)(ot * 128 + o_l) * 9216 + kb + kk];
    }
    __syncthreads();
#pragma unroll
    for (int r = 0; r < 8; ++r) {
        int e = tid + 256 * r;
        int kk = e >> 7, o_l = e & 127;
        Wt2[((size_t)ot * 9216 + kb + kk) * 128 + o_l] = t[kk][o_l];
    }
}

// ---------------- conv 3x3 + bias + relu ----------------
// tile: O=128, H=2, W=64. 256 thr: tx=tid&7 (w=tx*8), hloc=(tid>>3)&1, ty=tid>>4 (o=ty*8)
// LDS: Wb[2][36k][128o] + Ib[2][4c][4r][64w]  (CK=4, double buffered) = 45KB
__global__ __launch_bounds__(256, 1) void conv3x3_kernel(
    const float* __restrict__ Wt2, const float* __restrict__ in,
    const float* __restrict__ zerop, const float* __restrict__ bc,
    float* __restrict__ xout)
{
    __shared__ __align__(16) float Wb[2][36 * 128];
    __shared__ __align__(16) float Ib[2][4 * 4 * 64];

    const int h0 = blockIdx.x * 2;
    const int ot = blockIdx.y;
    const int b  = blockIdx.z;
    const int tid = threadIdx.x;
    const int tx = tid & 7;
    const int hloc = (tid >> 3) & 1;
    const int ty = tid >> 4;
    const int wv = tid >> 6;
    const int ln = tid & 63;
    const int w0i = tx * 8;

    // staging lane mapping
    const int r_ln = ln >> 4;
    const int wc_ln = (ln & 15) * 4;
    const int hin = h0 - 1 + r_ln;
    const bool hok = (hin >= 0) && (hin < 64);
    const float* isrc = in + ((size_t)(b * 1024) * 64 + (hok ? hin : 0)) * 64 + wc_ln;
    const float* zsrc = zerop + ln * 4;
    const float* wsrc = Wt2 + (size_t)ot * 9216 * 128 + ln * 4;

    auto stage = [&](int cc, int buf) {
        // weights: 18 x 1KB calls (2 k-rows each), split over 4 waves
        const float* wsB = wsrc + (size_t)cc * 36 * 128;
#pragma unroll
        for (int j = 0; j < 5; ++j) {
            int m = wv + 4 * j;
            if (m < 18)
                gl16(wsB + (size_t)(m * 2) * 128, &Wb[buf][m * 2 * 128]);
        }
        // input: 4 channels, one 1KB call per wave (4 rows x 64)
        const float* s = hok ? (isrc + (size_t)(cc * 4 + wv) * 4096) : zsrc;
        gl16(s, &Ib[buf][wv * 256]);
    };

    float acc[8][8], accc[8][8];
#pragma unroll
    for (int i = 0; i < 8; ++i)
#pragma unroll
        for (int j = 0; j < 8; ++j) { acc[i][j] = 0.f; accc[i][j] = 0.f; }

    stage(0, 0);
    __syncthreads();

    for (int cc = 0; cc < 256; ++cc) {
        const int buf = cc & 1;
        if (cc + 1 < 256) stage(cc + 1, buf ^ 1);

#pragma unroll
        for (int c = 0; c < 4; ++c) {
            const float* irow = &Ib[buf][c * 256 + hloc * 64];
            const float* wbase = &Wb[buf][c * 9 * 128 + ty * 8];
#pragma unroll
            for (int kh = 0; kh < 3; ++kh) {
                const float* row = irow + kh * 64;
                float4 v0 = *(const float4*)(row + w0i);
                float4 v1 = *(const float4*)(row + w0i + 4);
                float xl = (tx == 0) ? 0.f : row[w0i - 1];
                float xrr = (tx == 7) ? 0.f : row[w0i + 8];
                float xr[10];
                xr[0] = xl; xr[1] = v0.x; xr[2] = v0.y; xr[3] = v0.z; xr[4] = v0.w;
                xr[5] = v1.x; xr[6] = v1.y; xr[7] = v1.z; xr[8] = v1.w; xr[9] = xrr;
#pragma unroll
                for (int kw = 0; kw < 3; ++kw) {
                    const float* wr = wbase + (kh * 3 + kw) * 128;
                    float4 wa = *(const float4*)wr;
                    float4 wb2 = *(const float4*)(wr + 4);
#pragma unroll
                    for (int jw = 0; jw < 8; ++jw) {
                        float xv = xr[kw + jw];
                        accc[0][jw] += wa.x * xv;
                        accc[1][jw] += wa.y * xv;
                        accc[2][jw] += wa.z * xv;
                        accc[3][jw] += wa.w * xv;
                        accc[4][jw] += wb2.x * xv;
                        accc[5][jw] += wb2.y * xv;
                        accc[6][jw] += wb2.z * xv;
                        accc[7][jw] += wb2.w * xv;
                    }
                }
            }
        }
        if (cc & 1) {   // fold every 8 channels (bitwise-identical to R0 order)
#pragma unroll
            for (int i = 0; i < 8; ++i)
#pragma unroll
                for (int j = 0; j < 8; ++j) { acc[i][j] += accc[i][j]; accc[i][j] = 0.f; }
        }
        __syncthreads();
    }

    const int h = h0 + hloc;
#pragma unroll
    for (int i = 0; i < 8; ++i) {
        int o = ot * 128 + ty * 8 + i;
        float bias = bc[o];
        float4 r0, r1;
        r0.x = fmaxf(acc[i][0] + bias, 0.f);
        r0.y = fmaxf(acc[i][1] + bias, 0.f);
        r0.z = fmaxf(acc[i][2] + bias, 0.f);
        r0.w = fmaxf(acc[i][3] + bias, 0.f);
        r1.x = fmaxf(acc[i][4] + bias, 0.f);
        r1.y = fmaxf(acc[i][5] + bias, 0.f);
        r1.z = fmaxf(acc[i][6] + bias, 0.f);
        r1.w = fmaxf(acc[i][7] + bias, 0.f);
        size_t off = (((size_t)(b * 512 + o) * 64) + h) * 64 + w0i;
        *(float4*)&xout[off] = r0;
        *(float4*)&xout[off + 4] = r1;
    }
}

// ---------------- heads: 1x1 convs + softmax + decode + clip + filter ----------------
__global__ __launch_bounds__(256) void head_kernel(
    const float* __restrict__ x, const float* __restrict__ Wcls,
    const float* __restrict__ bcls, const float* __restrict__ Wbb,
    const float* __restrict__ bbb, const float* __restrict__ meta,
    ull* __restrict__ keys, float4* __restrict__ boxes)
{
    __shared__ __align__(16) float Wl[512 * 20]; // [c][j], 40 KB
    const int b = blockIdx.y, blk = blockIdx.x, tid = threadIdx.x;

#pragma unroll
    for (int r = 0; r < 40; ++r) {
        int L = tid + 256 * r;               // 0..10239
        int c = L / 20, j = L - 20 * c;
        Wl[c * 20 + j] = (j < 4) ? Wcls[j * 512 + c] : Wbb[(j - 4) * 512 + c];
    }
    __syncthreads();

    const int p = blk * 256 + tid;           // spatial position 0..4095
    const float* xb = x + (size_t)(b * 512) * 4096 + p;

    float acc[20];
#pragma unroll
    for (int j = 0; j < 20; ++j) acc[j] = 0.f;

    for (int c0 = 0; c0 < 512; c0 += 64) {
        float at[20];
#pragma unroll
        for (int j = 0; j < 20; ++j) at[j] = 0.f;
        for (int c = c0; c < c0 + 64; ++c) {
            float xv = xb[(size_t)c * 4096];
            const float4* wr = (const float4*)(Wl + c * 20);
            float4 w0 = wr[0], w1 = wr[1], w2 = wr[2], w3 = wr[3], w4 = wr[4];
            at[0] += w0.x * xv;  at[1] += w0.y * xv;  at[2] += w0.z * xv;  at[3] += w0.w * xv;
            at[4] += w1.x * xv;  at[5] += w1.y * xv;  at[6] += w1.z * xv;  at[7] += w1.w * xv;
            at[8] += w2.x * xv;  at[9] += w2.y * xv;  at[10] += w2.z * xv; at[11] += w2.w * xv;
            at[12] += w3.x * xv; at[13] += w3.y * xv; at[14] += w3.z * xv; at[15] += w3.w * xv;
            at[16] += w4.x * xv; at[17] += w4.y * xv; at[18] += w4.z * xv; at[19] += w4.w * xv;
        }
#pragma unroll
        for (int j = 0; j < 20; ++j) acc[j] += at[j];
    }

    float s[4], d[16];
#pragma unroll
    for (int j = 0; j < 4; ++j) s[j] = acc[j] + bcls[j];
#pragma unroll
    for (int j = 0; j < 16; ++j) d[j] = acc[4 + j] + bbb[j];

    float prob[4];
#pragma unroll
    for (int pr = 0; pr < 2; ++pr) {
        float m = fmaxf(s[pr], s[pr + 2]);
        float e0 = expf(s[pr] - m), e2 = expf(s[pr + 2] - m);
        float sum = e0 + e2;
        prob[pr] = e0 / sum;
        prob[pr + 2] = e2 / sum;
    }

    const float imh1 = meta[b * 3 + 0] - 1.0f;
    const float imw1 = meta[b * 3 + 1] - 1.0f;
    const float minsz = 16.0f * meta[b * 3 + 2];
    const int wp = p & 63, hp = p >> 6;
    const float cx = (float)(wp * 16 + 8), cy = (float)(hp * 16 + 8);

#pragma unroll
    for (int a = 0; a < 4; ++a) {
        float wa = (float)(64 << a);
        float pcx = d[4 * a + 0] * wa + cx;
        float pcy = d[4 * a + 1] * wa + cy;
        float pw = expf(d[4 * a + 2]) * wa;
        float ph = expf(d[4 * a + 3]) * wa;
        float x1 = pcx - 0.5f * pw, y1 = pcy - 0.5f * ph;
        float x2 = pcx + 0.5f * pw, y2 = pcy + 0.5f * ph;
        x1 = fminf(fmaxf(x1, 0.f), imw1);
        y1 = fminf(fmaxf(y1, 0.f), imh1);
        x2 = fminf(fmaxf(x2, 0.f), imw1);
        y2 = fminf(fmaxf(y2, 0.f), imh1);
        bool keep = (((x2 - x1) + 1.0f) >= minsz) && (((y2 - y1) + 1.0f) >= minsz);
        float sc = keep ? prob[a] : -__builtin_inff();
        int n = p * 4 + a;
        keys[b * 16384 + n] = ((ull)ordf(sc) << 32) | (ull)(unsigned)(16383 - n);
        float4 bx; bx.x = x1; bx.y = y1; bx.z = x2; bx.w = y2;
        boxes[b * 16384 + n] = bx;
    }
}

// ---------------- bitonic sort (descending) over uint64 keys ----------------
__global__ __launch_bounds__(512) void sort_local(ull* __restrict__ keys, int kfirst, int klast)
{
    __shared__ ull s[4096];
    const int b = blockIdx.y, chunk = blockIdx.x, tid = threadIdx.x;
    ull* g = keys + b * 16384 + chunk * 4096;
#pragma unroll
    for (int r = 0; r < 8; ++r) s[tid + 512 * r] = g[tid + 512 * r];
    __syncthreads();
    const int gbase = chunk * 4096;
    for (int k = kfirst; k <= klast; k <<= 1) {
        int j0 = (k >> 1) < 2048 ? (k >> 1) : 2048;
        for (int j = j0; j > 0; j >>= 1) {
#pragma unroll
            for (int pp = 0; pp < 4; ++pp) {
                int p = tid + 512 * pp;
                int i = ((p & ~(j - 1)) << 1) | (p & (j - 1));
                int l = i + j;
                ull a = s[i], c = s[l];
                bool up = (((gbase + i) & k) == 0);
                bool sw = up ? (a < c) : (c < a);
                if (sw) { s[i] = c; s[l] = a; }
            }
            __syncthreads();
        }
    }
#pragma unroll
    for (int r = 0; r < 8; ++r) g[tid + 512 * r] = s[tid + 512 * r];
}

__global__ __launch_bounds__(256) void sort_global_k(ull* __restrict__ keys, int k, int j)
{
    int t = blockIdx.x * 256 + threadIdx.x;
    int b = t >> 13, p = t & 8191;
    int i = ((p & ~(j - 1)) << 1) | (p & (j - 1));
    int l = i + j;
    ull* g = keys + b * 16384;
    ull a = g[i], c = g[l];
    bool up = ((i & k) == 0);
    bool sw = up ? (a < c) : (c < a);
    if (sw) { g[i] = c; g[l] = a; }
}

// ---------------- gather top-6000 sorted boxes ----------------
__global__ __launch_bounds__(256) void gather_kernel(
    const ull* __restrict__ keys, const float4* __restrict__ boxes,
    float4* __restrict__ bs, float* __restrict__ as_, ull* __restrict__ valid)
{
    const int b = blockIdx.y;
    const int i = blockIdx.x * 256 + threadIdx.x;
    bool fin = false;
    float4 box; box.x = 0.f; box.y = 0.f; box.z = 0.f; box.w = 0.f;
    float area = 1.f;
    if (i < 6000) {
        ull k = keys[b * 16384 + i];
        fin = ((unsigned)(k >> 32)) != NEGINF_ORD;
        int idx = 16383 - (int)(k & 0xFFFFFFFFull);
        box = boxes[b * 16384 + idx];
        area = ((box.z - box.x) + 1.0f) * ((box.w - box.y) + 1.0f);
    }
    bs[b * 6144 + i] = box;
    as_[b * 6144 + i] = area;
    ull m = __ballot(fin ? 1 : 0);
    if ((threadIdx.x & 63) == 0) valid[b * 96 + (i >> 6)] = m;
}

// ---------------- sequential greedy NMS with bitmask head scan ----------------
__global__ __launch_bounds__(1024) void nms_kernel(
    const float4* __restrict__ bs, const float* __restrict__ as_,
    const ull* __restrict__ valid, float* __restrict__ out)
{
    __shared__ unsigned alive[192];    // 6144 bits
    __shared__ int keepL[300];
    __shared__ int jsh;
    __shared__ float4 jbox_sh;
    __shared__ float jarea_sh;
    __shared__ int cur_sh;

    const int b = blockIdx.x, tid = threadIdx.x;

    if (tid < 96) {
        ull w = valid[b * 96 + tid];
        alive[tid * 2] = (unsigned)w;
        alive[tid * 2 + 1] = (unsigned)(w >> 32);
    }
    if (tid == 0) cur_sh = 0;
    __syncthreads();

    float4 box[6]; float area[6]; bool sf[6];
#pragma unroll
    for (int q = 0; q < 6; ++q) {
        int i = tid * 6 + q;
        box[q] = bs[b * 6144 + i];
        area[q] = as_[b * 6144 + i];
        sf[q] = !((alive[i >> 5] >> (i & 31)) & 1u);
    }
    __syncthreads();

    for (int t = 0; t < 300; ++t) {
        if (tid == 0) {
            int w = cur_sh;
            unsigned v = 0;
            while (w < 192 && (v = alive[w]) == 0u) ++w;
            int j;
            if (w < 192) {
                int bit = __ffs(v) - 1;
                j = w * 32 + bit;
                alive[w] = v & (v - 1);   // consume j
            } else {
                j = 0;
            }
            cur_sh = w;
            jsh = j; keepL[t] = j;
            jbox_sh = bs[b * 6144 + j];
            jarea_sh = as_[b * 6144 + j];
        }
        __syncthreads();
        const int j = jsh;
        const float4 jb = jbox_sh;
        const float ja = jarea_sh;
#pragma unroll
        for (int q = 0; q < 6; ++q) {
            int i = tid * 6 + q;
            if (i == j) sf[q] = true;
            if (!sf[q] && i > j) {
                float xx1 = fmaxf(jb.x, box[q].x);
                float yy1 = fmaxf(jb.y, box[q].y);
                float xx2 = fminf(jb.z, box[q].z);
                float yy2 = fminf(jb.w, box[q].w);
                float iw = fmaxf((xx2 - xx1) + 1.0f, 0.f);
                float ih = fmaxf((yy2 - yy1) + 1.0f, 0.f);
                float inter = iw * ih;
                float iou = inter / ((ja + area[q]) - inter);
                if (iou > 0.7f) {
                    sf[q] = true;
                    atomicAnd(&alive[i >> 5], ~(1u << (i & 31)));
                }
            }
        }
        __syncthreads();
    }

    if (tid < 300) {
        int j = keepL[tid];
        float4 bx = bs[b * 6144 + j];
        float* o = out + (size_t)(b * 300 + tid) * 5;
        o[0] = (float)b; o[1] = bx.x; o[2] = bx.y; o[3] = bx.z; o[4] = bx.w;
    }
}

// ---------------- launcher ----------------
extern "C" void kernel_launch(void* const* d_in, const int* in_sizes, int n_in,
                              void* d_out, int out_size, void* d_ws, size_t ws_size,
                              hipStream_t stream) {
    const float* feat  = (const float*)d_in[0];
    const float* meta  = (const float*)d_in[1];
    const float* Wconv = (const float*)d_in[3];
    const float* bconv = (const float*)d_in[4];
    const float* Wcls  = (const float*)d_in[5];
    const float* bcls  = (const float*)d_in[6];
    const float* Wbb   = (const float*)d_in[7];
    const float* bbb   = (const float*)d_in[8];
    float* out = (float*)d_out;

    char* ws = (char*)d_ws;
    float*  x     = (float*)(ws);                       // 16,777,216 B
    float*  Wt2   = (float*)(ws + 16777216);            // 18,874,368 B
    float*  zerop = (float*)(ws + 35651584);            //      4,096 B
    ull*    keys  = (ull*)(ws + 35655680);              //    262,144 B
    float4* boxes = (float4*)(ws + 35917824);           //  1,048,576 B
    float4* bsort = (float4*)(ws + 36966400);           //    196,608 B
    float*  asort = (float*)(ws + 37163008);            //     49,152 B
    ull*    valid = (ull*)(ws + 37212160);              //      1,536 B

    zero_fill<<<1, 256, 0, stream>>>(zerop);
    reorder_w<<<dim3(576, 4), 256, 0, stream>>>(Wconv, Wt2);
    conv3x3_kernel<<<dim3(32, 4, 2), 256, 0, stream>>>(Wt2, feat, zerop, bconv, x);
    head_kernel<<<dim3(16, 2), 256, 0, stream>>>(x, Wcls, bcls, Wbb, bbb, meta, keys, boxes);
    sort_local<<<dim3(4, 2), 512, 0, stream>>>(keys, 2, 4096);
    sort_global_k<<<64, 256, 0, stream>>>(keys, 8192, 4096);
    sort_local<<<dim3(4, 2), 512, 0, stream>>>(keys, 8192, 8192);
    sort_global_k<<<64, 256, 0, stream>>>(keys, 16384, 8192);
    sort_global_k<<<64, 256, 0, stream>>>(keys, 16384, 4096);
    sort_local<<<dim3(4, 2), 512, 0, stream>>>(keys, 16384, 16384);
    gather_kernel<<<dim3(24, 2), 256, 0, stream>>>(keys, boxes, bsort, asort, valid);
    nms_kernel<<<2, 1024, 0, stream>>>(bsort, asort, valid, out);
}